// Round 5
// baseline (469.489 us; speedup 1.0000x reference)
//
#include <hip/hip_runtime.h>

#define SLEN 4096
#define DIM  200
#define DP   224   // K-dim padded to 7*32
#define DPL  232   // LDS row stride for K-dim tiles (2-way-free for b128)
#define VD   208   // d padded to 13*16
#define VTL  72    // Vt / P LDS row stride

typedef __bf16 bf16t;
typedef bf16t bf16x8 __attribute__((ext_vector_type(8)));
typedef float f32x4 __attribute__((ext_vector_type(4)));

static __device__ __forceinline__ f32x4 mfma16(bf16x8 a, bf16x8 b, f32x4 c) {
    return __builtin_amdgcn_mfma_f32_16x16x32_bf16(a, b, c, 0, 0, 0);
}

static __device__ __forceinline__ unsigned short f2bf(float f) {
    unsigned int u = __float_as_uint(f);
    u += 0x7FFFu + ((u >> 16) & 1u);   // RNE
    return (unsigned short)(u >> 16);
}

static __device__ __forceinline__ uint2 pack4(float a, float b, float c, float d) {
    uint2 r;
    r.x = (unsigned)f2bf(a) | ((unsigned)f2bf(b) << 16);
    r.y = (unsigned)f2bf(c) | ((unsigned)f2bf(d) << 16);
    return r;
}

// ---------------------------------------------------------------------------
// Kernel 1: fused QKV projection for both modalities.
// grid 512: [mod(2) x 256 row-blocks of 64].  C[s,o] = sum_k x[s,k] W[o,k] + b[o]
// Q,K -> [unit][S][DP] bf16 (cols >=200 left as poison-tiny bf16, harmless)
// V   -> transposed [unit][VD][S] bf16, rows 200..207 zeroed.
// ---------------------------------------------------------------------------
__global__ __launch_bounds__(256, 2)
void proj_kernel(const float* __restrict__ x1, const float* __restrict__ x2,
                 const float* __restrict__ Wq, const float* __restrict__ bq,
                 const float* __restrict__ Wk, const float* __restrict__ bk,
                 const float* __restrict__ Wv, const float* __restrict__ bv,
                 unsigned short* __restrict__ Qg, unsigned short* __restrict__ Kg,
                 unsigned short* __restrict__ Vtg)
{
    __shared__ unsigned short x_lds[64 * DPL];
    __shared__ unsigned short w_lds[64 * DPL];
    __shared__ unsigned short vt_lds[64 * 66];

    const int tid = threadIdx.x;
    const int mod = blockIdx.x >> 8;
    const int rb  = blockIdx.x & 255;
    const int r0  = rb * 64;
    const int bidx = r0 >> 12;
    const int s0  = r0 & 4095;
    const int unit = mod * 4 + bidx;
    const float* __restrict__ x = mod ? x2 : x1;

    // stage x tile 64x200 fp32 -> bf16 LDS
    for (int i = tid; i < 3200; i += 256) {
        int r = i / 50, c = i % 50;
        const float4 v = *(const float4*)(x + (size_t)(r0 + r) * DIM + c * 4);
        *(uint2*)(x_lds + r * DPL + c * 4) = pack4(v.x, v.y, v.z, v.w);
    }
    {   // zero K-pads of x and w tiles (cols 200..231)
        int r = tid >> 2, c4 = tid & 3;
        uint2 z = make_uint2(0u, 0u);
        *(uint2*)(x_lds + r * DPL + 200 + c4 * 4) = z;
        *(uint2*)(x_lds + r * DPL + 216 + c4 * 4) = z;
        *(uint2*)(w_lds + r * DPL + 200 + c4 * 4) = z;
        *(uint2*)(w_lds + r * DPL + 216 + c4 * 4) = z;
    }
    __syncthreads();

    const int wv = tid >> 6, lane = tid & 63, ln = lane & 15, h = lane >> 4;

    bf16x8 afrag[7];
    #pragma unroll
    for (int kk = 0; kk < 7; ++kk)
        afrag[kk] = *(const bf16x8*)(x_lds + (wv * 16 + ln) * DPL + kk * 32 + 8 * h);

    for (int mmat = 0; mmat < 3; ++mmat) {
        const float* W  = (mmat == 0) ? Wq : (mmat == 1 ? Wk : Wv);
        const float* bi = (mmat == 0) ? bq : (mmat == 1 ? bk : bv);
        for (int t = 0; t < 4; ++t) {
            // stage 64 W rows (zeros beyond row 199)
            for (int i = tid; i < 3200; i += 256) {
                int r = i / 50, c = i % 50;
                int og = t * 64 + r;
                uint2 val = make_uint2(0u, 0u);
                if (og < DIM) {
                    const float4 v = *(const float4*)(W + (size_t)og * DIM + c * 4);
                    val = pack4(v.x, v.y, v.z, v.w);
                }
                *(uint2*)(w_lds + r * DPL + c * 4) = val;
            }
            __syncthreads();

            f32x4 acc[4];
            #pragma unroll
            for (int sub = 0; sub < 4; ++sub) acc[sub] = (f32x4){0.f, 0.f, 0.f, 0.f};
            #pragma unroll
            for (int kk = 0; kk < 7; ++kk) {
                #pragma unroll
                for (int sub = 0; sub < 4; ++sub) {
                    bf16x8 bfrag = *(const bf16x8*)(w_lds + (sub * 16 + ln) * DPL + kk * 32 + 8 * h);
                    acc[sub] = mfma16(afrag[kk], bfrag, acc[sub]);
                }
            }

            if (mmat < 2) {
                unsigned short* dst = (mmat == 0) ? Qg : Kg;
                #pragma unroll
                for (int sub = 0; sub < 4; ++sub) {
                    int og = t * 64 + sub * 16 + ln;
                    if (og < DIM) {
                        float bias = bi[og];
                        #pragma unroll
                        for (int r = 0; r < 4; ++r) {
                            int srow = s0 + wv * 16 + 4 * h + r;
                            dst[((size_t)unit * SLEN + srow) * DP + og] = f2bf(acc[sub][r] + bias);
                        }
                    }
                }
                __syncthreads();
            } else {
                // v: stage to LDS then transposed store (stride 66 -> ~conflict-free)
                #pragma unroll
                for (int sub = 0; sub < 4; ++sub) {
                    int og = t * 64 + sub * 16 + ln;
                    float bias = (og < DIM) ? bi[og] : 0.f;
                    #pragma unroll
                    for (int r = 0; r < 4; ++r) {
                        float val = (og < DIM) ? (acc[sub][r] + bias) : 0.f;
                        vt_lds[(wv * 16 + 4 * h + r) * 66 + sub * 16 + ln] = f2bf(val);
                    }
                }
                __syncthreads();
                for (int p = 0; p < 2; ++p) {
                    int idx = p * 256 + tid;
                    int dl = idx >> 3, cc = idx & 7;
                    int og = t * 64 + dl;
                    if (og < VD) {
                        unsigned short tmp[8];
                        #pragma unroll
                        for (int j = 0; j < 8; ++j)
                            tmp[j] = vt_lds[(cc * 8 + j) * 66 + dl];
                        *(uint4*)(Vtg + ((size_t)unit * VD + og) * SLEN + s0 + cc * 8) = *(uint4*)tmp;
                    }
                }
                __syncthreads();
            }
        }
    }
}

// ---------------------------------------------------------------------------
// Kernel 2: flash attention forward.  grid 256 = 8 units x 32 Q-tiles(128).
// u = bx&7 pins each unit's K/V working set (3.5 MB) to one XCD's L2.
// 8 waves, each owns 16 q rows; KV tiles of 64 staged in LDS.
// ---------------------------------------------------------------------------
__global__ __launch_bounds__(512, 2)
void attn_kernel(const unsigned short* __restrict__ Qg,
                 const unsigned short* __restrict__ Kg,
                 const unsigned short* __restrict__ Vtg,
                 float* __restrict__ Og)
{
    __shared__ unsigned short k_lds[64 * DPL];       // 29.7 KB
    __shared__ unsigned short vt_lds[VD * VTL];      // 30.0 KB
    __shared__ unsigned short p_lds[8 * 16 * VTL];   // 18.4 KB

    const int tid = threadIdx.x;
    const int u   = blockIdx.x & 7;
    const int qt  = blockIdx.x >> 3;
    const int wv = tid >> 6, lane = tid & 63, ln = lane & 15, h = lane >> 4;
    const size_t ubase = (size_t)u * SLEN;

    bf16x8 qfrag[7];
    {
        const size_t qoff = (ubase + qt * 128 + wv * 16 + ln) * DP;
        #pragma unroll
        for (int kk = 0; kk < 7; ++kk)
            qfrag[kk] = *(const bf16x8*)(Qg + qoff + kk * 32 + 8 * h);
    }

    float mrun[4], lrun[4];
    #pragma unroll
    for (int r = 0; r < 4; ++r) { mrun[r] = -1e30f; lrun[r] = 0.f; }
    f32x4 acc[13];
    #pragma unroll
    for (int d = 0; d < 13; ++d) acc[d] = (f32x4){0.f, 0.f, 0.f, 0.f};

    const float scale = 0.07071067811865475f;  // 1/sqrt(200)

    for (int t0 = 0; t0 < SLEN; t0 += 64) {
        // stage K tile [64][224] and Vt tile [208][64]
        #pragma unroll
        for (int it = 0; it < 4; ++it) {
            int i = it * 512 + tid;
            if (i < 1792) {
                int r = i / 28, c = i % 28;
                *(uint4*)(k_lds + r * DPL + c * 8) =
                    *(const uint4*)(Kg + (ubase + t0 + r) * DP + c * 8);
            }
            if (i < 1664) {
                int r = i >> 3, c = i & 7;
                *(uint4*)(vt_lds + r * VTL + c * 8) =
                    *(const uint4*)(Vtg + ((size_t)u * VD + r) * SLEN + t0 + c * 8);
            }
        }
        __syncthreads();

        // scores: S[s, t] = sum_k q[s,k] K[t,k]
        f32x4 sc[4];
        #pragma unroll
        for (int sub = 0; sub < 4; ++sub) sc[sub] = (f32x4){0.f, 0.f, 0.f, 0.f};
        #pragma unroll
        for (int kk = 0; kk < 7; ++kk) {
            #pragma unroll
            for (int sub = 0; sub < 4; ++sub) {
                bf16x8 bfrag = *(const bf16x8*)(k_lds + (sub * 16 + ln) * DPL + kk * 32 + 8 * h);
                sc[sub] = mfma16(qfrag[kk], bfrag, sc[sub]);
            }
        }

        // online softmax: per reg r, row = 4h+r; row is spread over the 16-lane group
        #pragma unroll
        for (int r = 0; r < 4; ++r) {
            float mx = fmaxf(fmaxf(sc[0][r], sc[1][r]), fmaxf(sc[2][r], sc[3][r]));
            mx = fmaxf(mx, __shfl_xor(mx, 1));
            mx = fmaxf(mx, __shfl_xor(mx, 2));
            mx = fmaxf(mx, __shfl_xor(mx, 4));
            mx = fmaxf(mx, __shfl_xor(mx, 8));
            mx *= scale;
            float mnew = fmaxf(mrun[r], mx);
            float alpha = __expf(mrun[r] - mnew);
            float rsum = 0.f;
            #pragma unroll
            for (int sub = 0; sub < 4; ++sub) {
                float p = __expf(sc[sub][r] * scale - mnew);
                rsum += p;
                p_lds[wv * (16 * VTL) + (4 * h + r) * VTL + sub * 16 + ln] = f2bf(p);
            }
            rsum += __shfl_xor(rsum, 1);
            rsum += __shfl_xor(rsum, 2);
            rsum += __shfl_xor(rsum, 4);
            rsum += __shfl_xor(rsum, 8);
            lrun[r] = lrun[r] * alpha + rsum;
            mrun[r] = mnew;
            #pragma unroll
            for (int d = 0; d < 13; ++d) acc[d][r] *= alpha;
        }

        // PV: O[s, d] += sum_t P[s,t] Vt[d,t]
        #pragma unroll
        for (int ks = 0; ks < 2; ++ks) {
            bf16x8 pfrag = *(const bf16x8*)(p_lds + wv * (16 * VTL) + ln * VTL + ks * 32 + 8 * h);
            #pragma unroll
            for (int d = 0; d < 13; ++d) {
                bf16x8 bfrag = *(const bf16x8*)(vt_lds + (d * 16 + ln) * VTL + ks * 32 + 8 * h);
                acc[d] = mfma16(pfrag, bfrag, acc[d]);
            }
        }
        __syncthreads();
    }

    #pragma unroll
    for (int r = 0; r < 4; ++r) {
        float inv = 1.f / lrun[r];
        int srow = qt * 128 + wv * 16 + 4 * h + r;
        #pragma unroll
        for (int d = 0; d < 13; ++d)
            Og[(ubase + srow) * VD + d * 16 + ln] = acc[d][r] * inv;
    }
}

// ---------------------------------------------------------------------------
// Kernel 3: out = (O1 + O2) @ Wo^T + bo.  grid 256 row-blocks of 64.
// ---------------------------------------------------------------------------
__global__ __launch_bounds__(256, 2)
void out_kernel(const float* __restrict__ Og, const float* __restrict__ Wo,
                const float* __restrict__ bo, float* __restrict__ out)
{
    __shared__ unsigned short a_lds[64 * DPL];
    __shared__ unsigned short w_lds[64 * DPL];

    const int tid = threadIdx.x;
    const int r0 = blockIdx.x * 64;
    const int bidx = r0 >> 12;
    const int s0 = r0 & 4095;

    const float* O1 = Og + (size_t)(0 + bidx) * SLEN * VD;
    const float* O2 = Og + (size_t)(4 + bidx) * SLEN * VD;

    for (int i = tid; i < 3200; i += 256) {
        int r = i / 50, c = i % 50;
        size_t off = (size_t)(s0 + r) * VD + c * 4;
        float4 a = *(const float4*)(O1 + off);
        float4 b = *(const float4*)(O2 + off);
        *(uint2*)(a_lds + r * DPL + c * 4) = pack4(a.x + b.x, a.y + b.y, a.z + b.z, a.w + b.w);
    }
    {
        int r = tid >> 2, c4 = tid & 3;
        uint2 z = make_uint2(0u, 0u);
        *(uint2*)(a_lds + r * DPL + 200 + c4 * 4) = z;
        *(uint2*)(a_lds + r * DPL + 216 + c4 * 4) = z;
        *(uint2*)(w_lds + r * DPL + 200 + c4 * 4) = z;
        *(uint2*)(w_lds + r * DPL + 216 + c4 * 4) = z;
    }
    __syncthreads();

    const int wv = tid >> 6, lane = tid & 63, ln = lane & 15, h = lane >> 4;
    bf16x8 afrag[7];
    #pragma unroll
    for (int kk = 0; kk < 7; ++kk)
        afrag[kk] = *(const bf16x8*)(a_lds + (wv * 16 + ln) * DPL + kk * 32 + 8 * h);

    for (int t = 0; t < 4; ++t) {
        for (int i = tid; i < 3200; i += 256) {
            int r = i / 50, c = i % 50;
            int og = t * 64 + r;
            uint2 val = make_uint2(0u, 0u);
            if (og < DIM) {
                const float4 v = *(const float4*)(Wo + (size_t)og * DIM + c * 4);
                val = pack4(v.x, v.y, v.z, v.w);
            }
            *(uint2*)(w_lds + r * DPL + c * 4) = val;
        }
        __syncthreads();

        f32x4 acc[4];
        #pragma unroll
        for (int sub = 0; sub < 4; ++sub) acc[sub] = (f32x4){0.f, 0.f, 0.f, 0.f};
        #pragma unroll
        for (int kk = 0; kk < 7; ++kk) {
            #pragma unroll
            for (int sub = 0; sub < 4; ++sub) {
                bf16x8 bfrag = *(const bf16x8*)(w_lds + (sub * 16 + ln) * DPL + kk * 32 + 8 * h);
                acc[sub] = mfma16(afrag[kk], bfrag, acc[sub]);
            }
        }

        #pragma unroll
        for (int sub = 0; sub < 4; ++sub) {
            int og = t * 64 + sub * 16 + ln;
            if (og < DIM) {
                float bias = bo[og];
                #pragma unroll
                for (int r = 0; r < 4; ++r) {
                    int row = r0 + wv * 16 + 4 * h + r;
                    out[(size_t)row * DIM + og] = acc[sub][r] + bias;
                }
            }
        }
        __syncthreads();
    }
}

// ---------------------------------------------------------------------------
extern "C" void kernel_launch(void* const* d_in, const int* in_sizes, int n_in,
                              void* d_out, int out_size, void* d_ws, size_t ws_size,
                              hipStream_t stream)
{
    const float* x1 = (const float*)d_in[0];
    const float* x2 = (const float*)d_in[1];
    const float* Wq = (const float*)d_in[2];
    const float* bq = (const float*)d_in[3];
    const float* Wk = (const float*)d_in[4];
    const float* bk = (const float*)d_in[5];
    const float* Wv = (const float*)d_in[6];
    const float* bv = (const float*)d_in[7];
    const float* Wo = (const float*)d_in[8];
    const float* bo = (const float*)d_in[9];

    unsigned short* Qg  = (unsigned short*)d_ws;
    unsigned short* Kg  = Qg + (size_t)8 * SLEN * DP;
    unsigned short* Vtg = Kg + (size_t)8 * SLEN * DP;
    float*          Og  = (float*)(Vtg + (size_t)8 * VD * SLEN);

    proj_kernel<<<dim3(512), dim3(256), 0, stream>>>(x1, x2, Wq, bq, Wk, bk, Wv, bv,
                                                     Qg, Kg, Vtg);
    attn_kernel<<<dim3(256), dim3(512), 0, stream>>>(Qg, Kg, Vtg, Og);
    out_kernel<<<dim3(256), dim3(256), 0, stream>>>(Og, Wo, bo, (float*)d_out);
}

// Round 7
// 409.068 us; speedup vs baseline: 1.1477x; 1.1477x over previous
//
#include <hip/hip_runtime.h>

#define SLEN 4096
#define DIM  200
#define DP   224   // K-dim padded to 7*32
#define DPL  232   // LDS row stride for K-dim tiles
#define VD   208   // d padded to 13*16
#define VTL  72    // Vt / P LDS row stride
#define HKV  2048  // KV half length (2 halves per sequence)

typedef __bf16 bf16t;
typedef bf16t bf16x8 __attribute__((ext_vector_type(8)));
typedef float f32x4 __attribute__((ext_vector_type(4)));

static __device__ __forceinline__ f32x4 mfma16(bf16x8 a, bf16x8 b, f32x4 c) {
    return __builtin_amdgcn_mfma_f32_16x16x32_bf16(a, b, c, 0, 0, 0);
}

static __device__ __forceinline__ unsigned short f2bf(float f) {
    unsigned int u = __float_as_uint(f);
    u += 0x7FFFu + ((u >> 16) & 1u);   // RNE
    return (unsigned short)(u >> 16);
}

static __device__ __forceinline__ float bf2f(unsigned short s) {
    return __uint_as_float((unsigned)s << 16);
}

static __device__ __forceinline__ uint2 pack4(float a, float b, float c, float d) {
    uint2 r;
    r.x = (unsigned)f2bf(a) | ((unsigned)f2bf(b) << 16);
    r.y = (unsigned)f2bf(c) | ((unsigned)f2bf(d) << 16);
    return r;
}

// ---------------------------------------------------------------------------
// Kernel 1: fused QKV projection for both modalities (unchanged from R0).
// ---------------------------------------------------------------------------
__global__ __launch_bounds__(256, 2)
void proj_kernel(const float* __restrict__ x1, const float* __restrict__ x2,
                 const float* __restrict__ Wq, const float* __restrict__ bq,
                 const float* __restrict__ Wk, const float* __restrict__ bk,
                 const float* __restrict__ Wv, const float* __restrict__ bv,
                 unsigned short* __restrict__ Qg, unsigned short* __restrict__ Kg,
                 unsigned short* __restrict__ Vtg)
{
    __shared__ unsigned short x_lds[64 * DPL];
    __shared__ unsigned short w_lds[64 * DPL];
    __shared__ unsigned short vt_lds[64 * 66];

    const int tid = threadIdx.x;
    const int mod = blockIdx.x >> 8;
    const int rb  = blockIdx.x & 255;
    const int r0  = rb * 64;
    const int bidx = r0 >> 12;
    const int s0  = r0 & 4095;
    const int unit = mod * 4 + bidx;
    const float* __restrict__ x = mod ? x2 : x1;

    for (int i = tid; i < 3200; i += 256) {
        int r = i / 50, c = i % 50;
        const float4 v = *(const float4*)(x + (size_t)(r0 + r) * DIM + c * 4);
        *(uint2*)(x_lds + r * DPL + c * 4) = pack4(v.x, v.y, v.z, v.w);
    }
    {
        int r = tid >> 2, c4 = tid & 3;
        uint2 z = make_uint2(0u, 0u);
        *(uint2*)(x_lds + r * DPL + 200 + c4 * 4) = z;
        *(uint2*)(x_lds + r * DPL + 216 + c4 * 4) = z;
        *(uint2*)(w_lds + r * DPL + 200 + c4 * 4) = z;
        *(uint2*)(w_lds + r * DPL + 216 + c4 * 4) = z;
    }
    __syncthreads();

    const int wv = tid >> 6, lane = tid & 63, ln = lane & 15, h = lane >> 4;

    bf16x8 afrag[7];
    #pragma unroll
    for (int kk = 0; kk < 7; ++kk)
        afrag[kk] = *(const bf16x8*)(x_lds + (wv * 16 + ln) * DPL + kk * 32 + 8 * h);

    for (int mmat = 0; mmat < 3; ++mmat) {
        const float* W  = (mmat == 0) ? Wq : (mmat == 1 ? Wk : Wv);
        const float* bi = (mmat == 0) ? bq : (mmat == 1 ? bk : bv);
        for (int t = 0; t < 4; ++t) {
            for (int i = tid; i < 3200; i += 256) {
                int r = i / 50, c = i % 50;
                int og = t * 64 + r;
                uint2 val = make_uint2(0u, 0u);
                if (og < DIM) {
                    const float4 v = *(const float4*)(W + (size_t)og * DIM + c * 4);
                    val = pack4(v.x, v.y, v.z, v.w);
                }
                *(uint2*)(w_lds + r * DPL + c * 4) = val;
            }
            __syncthreads();

            f32x4 acc[4];
            #pragma unroll
            for (int sub = 0; sub < 4; ++sub) acc[sub] = (f32x4){0.f, 0.f, 0.f, 0.f};
            #pragma unroll
            for (int kk = 0; kk < 7; ++kk) {
                #pragma unroll
                for (int sub = 0; sub < 4; ++sub) {
                    bf16x8 bfrag = *(const bf16x8*)(w_lds + (sub * 16 + ln) * DPL + kk * 32 + 8 * h);
                    acc[sub] = mfma16(afrag[kk], bfrag, acc[sub]);
                }
            }

            if (mmat < 2) {
                unsigned short* dst = (mmat == 0) ? Qg : Kg;
                #pragma unroll
                for (int sub = 0; sub < 4; ++sub) {
                    int og = t * 64 + sub * 16 + ln;
                    if (og < DIM) {
                        float bias = bi[og];
                        #pragma unroll
                        for (int r = 0; r < 4; ++r) {
                            int srow = s0 + wv * 16 + 4 * h + r;
                            dst[((size_t)unit * SLEN + srow) * DP + og] = f2bf(acc[sub][r] + bias);
                        }
                    }
                }
                __syncthreads();
            } else {
                #pragma unroll
                for (int sub = 0; sub < 4; ++sub) {
                    int og = t * 64 + sub * 16 + ln;
                    float bias = (og < DIM) ? bi[og] : 0.f;
                    #pragma unroll
                    for (int r = 0; r < 4; ++r) {
                        float val = (og < DIM) ? (acc[sub][r] + bias) : 0.f;
                        vt_lds[(wv * 16 + 4 * h + r) * 66 + sub * 16 + ln] = f2bf(val);
                    }
                }
                __syncthreads();
                for (int p = 0; p < 2; ++p) {
                    int idx = p * 256 + tid;
                    int dl = idx >> 3, cc = idx & 7;
                    int og = t * 64 + dl;
                    if (og < VD) {
                        unsigned short tmp[8];
                        #pragma unroll
                        for (int j = 0; j < 8; ++j)
                            tmp[j] = vt_lds[(cc * 8 + j) * 66 + dl];
                        *(uint4*)(Vtg + ((size_t)unit * VD + og) * SLEN + s0 + cc * 8) = *(uint4*)tmp;
                    }
                }
                __syncthreads();
            }
        }
    }
}

// ---------------------------------------------------------------------------
// Kernel 2: flash attention forward, KV-split by 2.
// grid 512 = hf(2) x 32 Q-tiles x 8 units; u = bx&7 keeps XCD/L2 pinning.
// Each block: 128 Q rows x 2048 KV (32 iters of 64).  Stores UNNORMALIZED
// A (bf16) into Ap[hf*8+u] plus per-row (m,l) into Ml.  Defer-max (T13).
// ---------------------------------------------------------------------------
__global__ __launch_bounds__(512, 4)
void attn_kernel(const unsigned short* __restrict__ Qg,
                 const unsigned short* __restrict__ Kg,
                 const unsigned short* __restrict__ Vtg,
                 unsigned short* __restrict__ Ap,
                 float2* __restrict__ Mlg)
{
    __shared__ unsigned short k_lds[64 * DPL];       // 29.7 KB
    __shared__ unsigned short vt_lds[VD * VTL];      // 30.0 KB
    __shared__ unsigned short p_lds[8 * 16 * VTL];   // 18.4 KB

    const int tid = threadIdx.x;
    const int u   = blockIdx.x & 7;
    const int qt  = (blockIdx.x >> 3) & 31;
    const int hf  = blockIdx.x >> 8;
    const int wv = tid >> 6, lane = tid & 63, ln = lane & 15, h = lane >> 4;
    const size_t ubase = (size_t)u * SLEN;

    bf16x8 qfrag[7];
    {
        const size_t qoff = (ubase + qt * 128 + wv * 16 + ln) * DP;
        #pragma unroll
        for (int kk = 0; kk < 7; ++kk)
            qfrag[kk] = *(const bf16x8*)(Qg + qoff + kk * 32 + 8 * h);
    }

    float mrun[4], lrun[4];
    #pragma unroll
    for (int r = 0; r < 4; ++r) { mrun[r] = -1e30f; lrun[r] = 0.f; }
    f32x4 acc[13];
    #pragma unroll
    for (int d = 0; d < 13; ++d) acc[d] = (f32x4){0.f, 0.f, 0.f, 0.f};

    const float scale = 0.07071067811865475f;  // 1/sqrt(200)
    const int t_beg = hf * HKV;

    for (int t0 = t_beg; t0 < t_beg + HKV; t0 += 64) {
        // stage K tile [64][224] and Vt tile [208][64]
        #pragma unroll
        for (int it = 0; it < 4; ++it) {
            int i = it * 512 + tid;
            if (i < 1792) {
                int r = i / 28, c = i % 28;
                *(uint4*)(k_lds + r * DPL + c * 8) =
                    *(const uint4*)(Kg + (ubase + t0 + r) * DP + c * 8);
            }
            if (i < 1664) {
                int r = i >> 3, c = i & 7;
                *(uint4*)(vt_lds + r * VTL + c * 8) =
                    *(const uint4*)(Vtg + ((size_t)u * VD + r) * SLEN + t0 + c * 8);
            }
        }
        __syncthreads();

        // scores: S[s, t] = sum_k q[s,k] K[t,k]
        f32x4 sc[4];
        #pragma unroll
        for (int sub = 0; sub < 4; ++sub) sc[sub] = (f32x4){0.f, 0.f, 0.f, 0.f};
        #pragma unroll
        for (int kk = 0; kk < 7; ++kk) {
            #pragma unroll
            for (int sub = 0; sub < 4; ++sub) {
                bf16x8 bfrag = *(const bf16x8*)(k_lds + (sub * 16 + ln) * DPL + kk * 32 + 8 * h);
                sc[sub] = mfma16(qfrag[kk], bfrag, sc[sub]);
            }
        }

        // row maxima (per reg r, row = 4h+r spread over 16-lane group)
        float mxs[4];
        #pragma unroll
        for (int r = 0; r < 4; ++r) {
            float mx = fmaxf(fmaxf(sc[0][r], sc[1][r]), fmaxf(sc[2][r], sc[3][r]));
            mx = fmaxf(mx, __shfl_xor(mx, 1));
            mx = fmaxf(mx, __shfl_xor(mx, 2));
            mx = fmaxf(mx, __shfl_xor(mx, 4));
            mx = fmaxf(mx, __shfl_xor(mx, 8));
            mxs[r] = mx * scale;
        }

        // T13 defer-max: only rescale when some row's max grew by > 8
        int need = (mxs[0] > mrun[0] + 8.f) | (mxs[1] > mrun[1] + 8.f) |
                   (mxs[2] > mrun[2] + 8.f) | (mxs[3] > mrun[3] + 8.f);
        if (__any(need)) {
            #pragma unroll
            for (int r = 0; r < 4; ++r) {
                float mnew = fmaxf(mrun[r], mxs[r]);
                float alpha = __expf(mrun[r] - mnew);
                lrun[r] *= alpha;
                #pragma unroll
                for (int d = 0; d < 13; ++d) acc[d][r] *= alpha;
                mrun[r] = mnew;
            }
        }

        #pragma unroll
        for (int r = 0; r < 4; ++r) {
            float rsum = 0.f;
            #pragma unroll
            for (int sub = 0; sub < 4; ++sub) {
                float p = __expf(sc[sub][r] * scale - mrun[r]);
                rsum += p;
                p_lds[wv * (16 * VTL) + (4 * h + r) * VTL + sub * 16 + ln] = f2bf(p);
            }
            rsum += __shfl_xor(rsum, 1);
            rsum += __shfl_xor(rsum, 2);
            rsum += __shfl_xor(rsum, 4);
            rsum += __shfl_xor(rsum, 8);
            lrun[r] += rsum;
        }

        // PV: A[s, d] += sum_t P[s,t] Vt[d,t]
        #pragma unroll
        for (int ks = 0; ks < 2; ++ks) {
            bf16x8 pfrag = *(const bf16x8*)(p_lds + wv * (16 * VTL) + ln * VTL + ks * 32 + 8 * h);
            #pragma unroll
            for (int d = 0; d < 13; ++d) {
                bf16x8 bfrag = *(const bf16x8*)(vt_lds + (d * 16 + ln) * VTL + ks * 32 + 8 * h);
                acc[d] = mfma16(pfrag, bfrag, acc[d]);
            }
        }
        __syncthreads();
    }

    // store unnormalized A (bf16) + (m, l) per row
    const int slab = hf * 8 + u;
    unsigned short* Adst = Ap + (size_t)slab * SLEN * VD;
    #pragma unroll
    for (int r = 0; r < 4; ++r) {
        int srow = qt * 128 + wv * 16 + 4 * h + r;
        #pragma unroll
        for (int d = 0; d < 13; ++d)
            Adst[(size_t)srow * VD + d * 16 + ln] = f2bf(acc[d][r]);
        if (ln == 0)
            Mlg[(size_t)slab * SLEN + srow] = make_float2(mrun[r], lrun[r]);
    }
}

// ---------------------------------------------------------------------------
// Kernel 3: combine KV-halves + fused = a1 + a2, then @ Wo^T + bo.
// grid 256 row-blocks of 64.
// ---------------------------------------------------------------------------
__global__ __launch_bounds__(256, 2)
void out_kernel(const unsigned short* __restrict__ Ap,
                const float2* __restrict__ Mlg,
                const float* __restrict__ Wo,
                const float* __restrict__ bo, float* __restrict__ out)
{
    __shared__ unsigned short a_lds[64 * DPL];
    __shared__ unsigned short w_lds[64 * DPL];

    const int tid = threadIdx.x;
    const int r0 = blockIdx.x * 64;
    const int bidx = r0 >> 12;
    const int s0 = r0 & 4095;

    // slabs: mod1 = {bidx, 8+bidx}, mod2 = {4+bidx, 12+bidx}
    const unsigned short* A1a = Ap + (size_t)(bidx)      * SLEN * VD;
    const unsigned short* A1b = Ap + (size_t)(8 + bidx)  * SLEN * VD;
    const unsigned short* A2a = Ap + (size_t)(4 + bidx)  * SLEN * VD;
    const unsigned short* A2b = Ap + (size_t)(12 + bidx) * SLEN * VD;
    const float2* M1a = Mlg + (size_t)(bidx)      * SLEN;
    const float2* M1b = Mlg + (size_t)(8 + bidx)  * SLEN;
    const float2* M2a = Mlg + (size_t)(4 + bidx)  * SLEN;
    const float2* M2b = Mlg + (size_t)(12 + bidx) * SLEN;

    for (int i = tid; i < 3200; i += 256) {
        int r = i / 50, c = i % 50;
        int srow = s0 + r;
        size_t off = (size_t)srow * VD + c * 4;

        float2 ml1a = M1a[srow], ml1b = M1b[srow];
        float2 ml2a = M2a[srow], ml2b = M2b[srow];
        float M1 = fmaxf(ml1a.x, ml1b.x);
        float w1a = __expf(ml1a.x - M1), w1b = __expf(ml1b.x - M1);
        float inv1 = 1.f / (ml1a.y * w1a + ml1b.y * w1b);
        float M2 = fmaxf(ml2a.x, ml2b.x);
        float w2a = __expf(ml2a.x - M2), w2b = __expf(ml2b.x - M2);
        float inv2 = 1.f / (ml2a.y * w2a + ml2b.y * w2b);

        uint2 pa = *(const uint2*)(A1a + off);
        uint2 pb = *(const uint2*)(A1b + off);
        uint2 qa = *(const uint2*)(A2a + off);
        uint2 qb = *(const uint2*)(A2b + off);

        float f[4];
        f[0] = (bf2f((unsigned short)(pa.x & 0xffff)) * w1a + bf2f((unsigned short)(pb.x & 0xffff)) * w1b) * inv1
             + (bf2f((unsigned short)(qa.x & 0xffff)) * w2a + bf2f((unsigned short)(qb.x & 0xffff)) * w2b) * inv2;
        f[1] = (bf2f((unsigned short)(pa.x >> 16))    * w1a + bf2f((unsigned short)(pb.x >> 16))    * w1b) * inv1
             + (bf2f((unsigned short)(qa.x >> 16))    * w2a + bf2f((unsigned short)(qb.x >> 16))    * w2b) * inv2;
        f[2] = (bf2f((unsigned short)(pa.y & 0xffff)) * w1a + bf2f((unsigned short)(pb.y & 0xffff)) * w1b) * inv1
             + (bf2f((unsigned short)(qa.y & 0xffff)) * w2a + bf2f((unsigned short)(qb.y & 0xffff)) * w2b) * inv2;
        f[3] = (bf2f((unsigned short)(pa.y >> 16))    * w1a + bf2f((unsigned short)(pb.y >> 16))    * w1b) * inv1
             + (bf2f((unsigned short)(qa.y >> 16))    * w2a + bf2f((unsigned short)(qb.y >> 16))    * w2b) * inv2;

        *(uint2*)(a_lds + r * DPL + c * 4) = pack4(f[0], f[1], f[2], f[3]);
    }
    {
        int r = tid >> 2, c4 = tid & 3;
        uint2 z = make_uint2(0u, 0u);
        *(uint2*)(a_lds + r * DPL + 200 + c4 * 4) = z;
        *(uint2*)(a_lds + r * DPL + 216 + c4 * 4) = z;
        *(uint2*)(w_lds + r * DPL + 200 + c4 * 4) = z;
        *(uint2*)(w_lds + r * DPL + 216 + c4 * 4) = z;
    }
    __syncthreads();

    const int wv = tid >> 6, lane = tid & 63, ln = lane & 15, h = lane >> 4;
    bf16x8 afrag[7];
    #pragma unroll
    for (int kk = 0; kk < 7; ++kk)
        afrag[kk] = *(const bf16x8*)(a_lds + (wv * 16 + ln) * DPL + kk * 32 + 8 * h);

    for (int t = 0; t < 4; ++t) {
        for (int i = tid; i < 3200; i += 256) {
            int r = i / 50, c = i % 50;
            int og = t * 64 + r;
            uint2 val = make_uint2(0u, 0u);
            if (og < DIM) {
                const float4 v = *(const float4*)(Wo + (size_t)og * DIM + c * 4);
                val = pack4(v.x, v.y, v.z, v.w);
            }
            *(uint2*)(w_lds + r * DPL + c * 4) = val;
        }
        __syncthreads();

        f32x4 acc[4];
        #pragma unroll
        for (int sub = 0; sub < 4; ++sub) acc[sub] = (f32x4){0.f, 0.f, 0.f, 0.f};
        #pragma unroll
        for (int kk = 0; kk < 7; ++kk) {
            #pragma unroll
            for (int sub = 0; sub < 4; ++sub) {
                bf16x8 bfrag = *(const bf16x8*)(w_lds + (sub * 16 + ln) * DPL + kk * 32 + 8 * h);
                acc[sub] = mfma16(afrag[kk], bfrag, acc[sub]);
            }
        }

        #pragma unroll
        for (int sub = 0; sub < 4; ++sub) {
            int og = t * 64 + sub * 16 + ln;
            if (og < DIM) {
                float bias = bo[og];
                #pragma unroll
                for (int r = 0; r < 4; ++r) {
                    int row = r0 + wv * 16 + 4 * h + r;
                    out[(size_t)row * DIM + og] = acc[sub][r] + bias;
                }
            }
        }
        __syncthreads();
    }
}

// ---------------------------------------------------------------------------
extern "C" void kernel_launch(void* const* d_in, const int* in_sizes, int n_in,
                              void* d_out, int out_size, void* d_ws, size_t ws_size,
                              hipStream_t stream)
{
    const float* x1 = (const float*)d_in[0];
    const float* x2 = (const float*)d_in[1];
    const float* Wq = (const float*)d_in[2];
    const float* bq = (const float*)d_in[3];
    const float* Wk = (const float*)d_in[4];
    const float* bk = (const float*)d_in[5];
    const float* Wv = (const float*)d_in[6];
    const float* bv = (const float*)d_in[7];
    const float* Wo = (const float*)d_in[8];
    const float* bo = (const float*)d_in[9];

    unsigned short* Qg  = (unsigned short*)d_ws;
    unsigned short* Kg  = Qg + (size_t)8 * SLEN * DP;
    unsigned short* Vtg = Kg + (size_t)8 * SLEN * DP;
    unsigned short* Apg = Vtg + (size_t)8 * VD * SLEN;             // 16 slabs bf16
    float2*         Mlg = (float2*)(Apg + (size_t)16 * SLEN * VD); // 16 x S x (m,l)

    proj_kernel<<<dim3(512), dim3(256), 0, stream>>>(x1, x2, Wq, bq, Wk, bk, Wv, bv,
                                                     Qg, Kg, Vtg);
    attn_kernel<<<dim3(512), dim3(512), 0, stream>>>(Qg, Kg, Vtg, Apg, Mlg);
    out_kernel<<<dim3(256), dim3(256), 0, stream>>>(Apg, Mlg, Wo, bo, (float*)d_out);
}